// Round 1
// baseline (195.492 us; speedup 1.0000x reference)
//
#include <hip/hip_runtime.h>

namespace {

constexpr int   kC   = 80;
constexpr int   kD   = 8525;
constexpr int   kB   = 64;
constexpr float kEps = 1e-6f;
constexpr int   kOC  = kC + 5;  // 85 channels in outs
constexpr int   kGC  = kC + 8;  // 88 channels in gres
constexpr int   kBlk = 256;

__device__ __forceinline__ float wave_reduce(float v) {
#pragma unroll
  for (int o = 32; o > 0; o >>= 1) v += __shfl_down(v, o, 64);
  return v;
}

__global__ __launch_bounds__(kBlk) void floss_main(
    const float* __restrict__ outs, const float* __restrict__ gres,
    const float* __restrict__ grids, const int* __restrict__ nums_pos,
    float* __restrict__ partials) {
  const unsigned N = (unsigned)kB * kD * kOC;  // 46,376,000
  float acc_main = 0.f;   // cls_pos + cls_neg + conf, already scaled by 1/(B*np)
  float acc_reg  = 0.f;   // sum (1-giou)*gcenter*mask_pos
  float acc_np   = 0.f;   // sum mask_pos
  const unsigned stride = gridDim.x * blockDim.x;
  for (unsigned i = blockIdx.x * blockDim.x + threadIdx.x; i < N; i += stride) {
    const unsigned row = i / kOC;          // b*D + d
    const int c = (int)(i - row * kOC);
    const int b = (int)(row / kD);
    const float scale = 1.0f / ((float)kB * (float)nums_pos[b]);
    if (c < kC) {
      const float x = outs[i];
      const float p = 1.0f / (1.0f + __expf(-x));
      const float g = gres[(size_t)row * kGC + c];
      float l;
      if (g == 1.0f) {
        const float om = 1.0f - p;
        l = -0.25f * om * om * __logf(p + kEps);
      } else {
        l = -0.75f * p * p * __logf(1.0f - p + kEps);
      }
      acc_main += l * scale;
    } else if (c == kC) {
      // conf BCE term (mask_pp)
      if (gres[(size_t)row * kGC + kC + 5] == 1.0f) {
        const float p = 1.0f / (1.0f + __expf(-outs[i]));
        acc_main += -5.0f * __logf(p + kEps) * scale;
      }
    } else if (c == kC + 1) {
      // one lane per row handles the GIoU regression term + npos count
      if (gres[(size_t)row * kGC + kC + 6] == 1.0f) {
        acc_np += 1.0f;
        const int d = (int)(row - (unsigned)b * kD);
        const float gx = grids[2 * d + 0];
        const float gy = grids[2 * d + 1];
        const float* po = outs + (size_t)row * kOC + kC + 1;
        const float p0 = gx - po[0], p1 = gy - po[1];
        const float p2 = gx + po[2], p3 = gy + po[3];
        const float* gg = gres + (size_t)row * kGC + kC + 1;
        const float g0 = gg[0], g1 = gg[1], g2 = gg[2], g3 = gg[3];
        const float iw = fmaxf(fminf(p2, g2) - fmaxf(p0, g0), 0.f);
        const float ih = fmaxf(fminf(p3, g3) - fmaxf(p1, g1), 0.f);
        const float inter = iw * ih;
        const float ap = fmaxf(p2 - p0, 0.f) * fmaxf(p3 - p1, 0.f);
        const float ag = fmaxf(g2 - g0, 0.f) * fmaxf(g3 - g1, 0.f);
        const float un = ap + ag - inter;
        const float iou = inter / (un + kEps);
        const float ca = (fmaxf(p2, g2) - fminf(p0, g0)) *
                         (fmaxf(p3, g3) - fminf(p1, g1));
        const float giou = iou - (ca - un) / (ca + kEps);
        acc_reg += (1.0f - giou) * gres[(size_t)row * kGC + kC];
      }
    }
    // c in [82,84]: nothing (those outs values are consumed by the c==81 lane)
  }

  __shared__ float sm[3][kBlk / 64];
  const float vm = wave_reduce(acc_main);
  const float vr = wave_reduce(acc_reg);
  const float vn = wave_reduce(acc_np);
  const int lane = threadIdx.x & 63;
  const int w    = threadIdx.x >> 6;
  if (lane == 0) { sm[0][w] = vm; sm[1][w] = vr; sm[2][w] = vn; }
  __syncthreads();
  if (threadIdx.x == 0) {
    float m = 0.f, r = 0.f, n = 0.f;
#pragma unroll
    for (int j = 0; j < kBlk / 64; ++j) { m += sm[0][j]; r += sm[1][j]; n += sm[2][j]; }
    partials[blockIdx.x * 3 + 0] = m;
    partials[blockIdx.x * 3 + 1] = r;
    partials[blockIdx.x * 3 + 2] = n;
  }
}

__global__ __launch_bounds__(kBlk) void floss_final(
    const float* __restrict__ partials, int nblk, float* __restrict__ out) {
  float m = 0.f, r = 0.f, n = 0.f;
  for (int i = threadIdx.x; i < nblk; i += kBlk) {
    m += partials[i * 3 + 0];
    r += partials[i * 3 + 1];
    n += partials[i * 3 + 2];
  }
  __shared__ float sm[3][kBlk / 64];
  m = wave_reduce(m); r = wave_reduce(r); n = wave_reduce(n);
  const int lane = threadIdx.x & 63;
  const int w    = threadIdx.x >> 6;
  if (lane == 0) { sm[0][w] = m; sm[1][w] = r; sm[2][w] = n; }
  __syncthreads();
  if (threadIdx.x == 0) {
    float tm = 0.f, tr = 0.f, tn = 0.f;
#pragma unroll
    for (int j = 0; j < kBlk / 64; ++j) { tm += sm[0][j]; tr += sm[1][j]; tn += sm[2][j]; }
    out[0] = tm + 5.0f * tr / fmaxf(tn, 1.0f);
  }
}

}  // namespace

extern "C" void kernel_launch(void* const* d_in, const int* in_sizes, int n_in,
                              void* d_out, int out_size, void* d_ws, size_t ws_size,
                              hipStream_t stream) {
  const float* outs     = (const float*)d_in[0];
  const float* gres     = (const float*)d_in[1];
  const float* grids    = (const float*)d_in[2];
  const int*   nums_pos = (const int*)d_in[3];
  float* partials = (float*)d_ws;

  int nblk = 2048;  // 256 CUs x 8 blocks/CU; grid-stride covers the rest
  const size_t need = (size_t)nblk * 3 * sizeof(float);
  if (ws_size < need) nblk = (int)(ws_size / (3 * sizeof(float)));

  floss_main<<<nblk, kBlk, 0, stream>>>(outs, gres, grids, nums_pos, partials);
  floss_final<<<1, kBlk, 0, stream>>>(partials, nblk, (float*)d_out);
}

// Round 2
// 70.831 us; speedup vs baseline: 2.7600x; 2.7600x over previous
//
#include <hip/hip_runtime.h>

namespace {

constexpr int   kC    = 80;
constexpr int   kD    = 8525;
constexpr int   kB    = 64;
constexpr float kEps  = 1e-6f;
constexpr int   kOC   = 85;                 // outs channels
constexpr int   kGC   = 88;                 // gres channels
constexpr int   kBlk  = 256;
constexpr int   kPB   = kD * kOC;           // 724625 floats of outs per batch
constexpr int   kKpb  = 32;                 // stream blocks per batch item
constexpr int   kNA   = kB * kKpb;          // 2048 stream blocks
constexpr int   kChunk = (kPB + kKpb - 1) / kKpb;  // 22645
constexpr int   kNB   = 768;                // row blocks (launched first)
constexpr int   kNT   = kNA + kNB;          // total blocks in fused kernel

__device__ __forceinline__ float wave_reduce(float v) {
#pragma unroll
  for (int o = 32; o > 0; o >>= 1) v += __shfl_down(v, o, 64);
  return v;
}

__device__ __forceinline__ float sigmoidf(float x) {
  return 1.0f / (1.0f + __expf(-x));
}

__global__ __launch_bounds__(kBlk) void floss_fused(
    const float* __restrict__ outs, const float* __restrict__ gres,
    const float* __restrict__ grids, const int* __restrict__ nums_pos,
    float* __restrict__ partials) {
  const int bid = blockIdx.x;
  const int tid = threadIdx.x;
  float pm = 0.f, pr = 0.f, pn = 0.f;

  if (bid < kNB) {
    // ---------------- row path: conf BCE + pos-correction + GIoU ----------
    const int nrow = kB * kD;
    for (int row = bid * kBlk + tid; row < nrow; row += kNB * kBlk) {
      const int b = row / kD;
      const int d = row - b * kD;
      const size_t gbase = (size_t)row * kGC;
      const float4 t0 = *(const float4*)(gres + gbase + 80);  // gc, l, t, r
      const float4 t1 = *(const float4*)(gres + gbase + 84);  // b, mpp, mpos, 0
      const float scale = 1.0f / (64.0f * (float)nums_pos[b]);
      if (t1.y == 1.0f) {  // mask_pp -> conf BCE
        const float pc = sigmoidf(outs[(size_t)row * kOC + kC]);
        pm += -5.0f * __logf(pc + kEps) * scale;
      }
      if (t1.z == 1.0f) {  // mask_pos
        pn += 1.0f;
        // find the one-hot label channel
        int lab = 0;
        const float4* gc = (const float4*)(gres + gbase);
#pragma unroll 5
        for (int j = 0; j < 20; ++j) {
          const float4 v = gc[j];
          if (v.x == 1.0f) lab = 4 * j;
          if (v.y == 1.0f) lab = 4 * j + 1;
          if (v.z == 1.0f) lab = 4 * j + 2;
          if (v.w == 1.0f) lab = 4 * j + 3;
        }
        // correction: + l_pos - l_neg at the labeled channel
        const float x = outs[(size_t)row * kOC + lab];
        const float p = sigmoidf(x);
        const float om = 1.0f - p;
        const float lp = -0.25f * om * om * __logf(p + kEps);
        const float ln = -0.75f * p * p * __logf(om + kEps);
        pm += (lp - ln) * scale;
        // GIoU regression term
        const float gx = grids[2 * d + 0];
        const float gy = grids[2 * d + 1];
        const float* po = outs + (size_t)row * kOC + kC + 1;
        const float p0 = gx - po[0], p1 = gy - po[1];
        const float p2 = gx + po[2], p3 = gy + po[3];
        const float g0 = t0.y, g1 = t0.z, g2 = t0.w, g3 = t1.x;
        const float iw = fmaxf(fminf(p2, g2) - fmaxf(p0, g0), 0.f);
        const float ih = fmaxf(fminf(p3, g3) - fmaxf(p1, g1), 0.f);
        const float inter = iw * ih;
        const float ap = fmaxf(p2 - p0, 0.f) * fmaxf(p3 - p1, 0.f);
        const float ag = fmaxf(g2 - g0, 0.f) * fmaxf(g3 - g1, 0.f);
        const float un = ap + ag - inter;
        const float iou = inter / (un + kEps);
        const float ca = (fmaxf(p2, g2) - fminf(p0, g0)) *
                         (fmaxf(p3, g3) - fminf(p1, g1));
        const float giou = iou - (ca - un) / (ca + kEps);
        pr += (1.0f - giou) * t0.x;
      }
    }
  } else {
    // ---------------- stream path: l_neg over all cls elements ------------
    const int sb = bid - kNB;
    const int b  = sb >> 5;   // / kKpb
    const int k  = sb & 31;   // % kKpb
    const long base = (long)b * kPB;
    const int  s = k * kChunk;
    const int  e = (s + kChunk < kPB) ? s + kChunk : kPB;
    const long gs = base + s;
    const long ge = base + e;
    const long gv = (gs + 3) & ~3L;                   // first float4-aligned
    const long gvend = gv + (((ge - gv) >> 2) << 2);  // end of vector region
    float acc = 0.f;  // sum of p^2 * log(1-p+eps), raw

    const int headc = (int)(gv - gs);
    if (tid < headc) {
      const long g = gs + tid;
      const unsigned c = (unsigned)(g - base) % 85u;
      if (c < 80u) {
        const float p = sigmoidf(outs[g]);
        acc += p * p * __logf(1.0f - p + kEps);
      }
    }
    const int tailc = (int)(ge - gvend);
    if (tid < tailc) {
      const long g = gvend + tid;
      const unsigned c = (unsigned)(g - base) % 85u;
      if (c < 80u) {
        const float p = sigmoidf(outs[g]);
        acc += p * p * __logf(1.0f - p + kEps);
      }
    }

    const int nvec = (int)((gvend - gv) >> 2);
    for (int v = tid; v < nvec; v += kBlk) {
      const long g = gv + 4L * v;
      const float4 val = *(const float4*)(outs + g);
      unsigned c = (unsigned)(g - base) % 85u;
      if (c < 80u) { const float p = sigmoidf(val.x); acc += p * p * __logf(1.0f - p + kEps); }
      c = (c + 1 >= 85u) ? 0u : c + 1;
      if (c < 80u) { const float p = sigmoidf(val.y); acc += p * p * __logf(1.0f - p + kEps); }
      c = (c + 1 >= 85u) ? 0u : c + 1;
      if (c < 80u) { const float p = sigmoidf(val.z); acc += p * p * __logf(1.0f - p + kEps); }
      c = (c + 1 >= 85u) ? 0u : c + 1;
      if (c < 80u) { const float p = sigmoidf(val.w); acc += p * p * __logf(1.0f - p + kEps); }
    }
    const float scale = 1.0f / (64.0f * (float)nums_pos[b]);
    pm = -0.75f * acc * scale;
  }

  // ---------------- block reduction + partial write -----------------------
  __shared__ float sm[3][kBlk / 64];
  const float vm = wave_reduce(pm);
  const float vr = wave_reduce(pr);
  const float vn = wave_reduce(pn);
  const int lane = tid & 63;
  const int w    = tid >> 6;
  if (lane == 0) { sm[0][w] = vm; sm[1][w] = vr; sm[2][w] = vn; }
  __syncthreads();
  if (tid == 0) {
    float m = 0.f, r = 0.f, n = 0.f;
#pragma unroll
    for (int j = 0; j < kBlk / 64; ++j) { m += sm[0][j]; r += sm[1][j]; n += sm[2][j]; }
    partials[bid * 3 + 0] = m;
    partials[bid * 3 + 1] = r;
    partials[bid * 3 + 2] = n;
  }
}

__global__ __launch_bounds__(kBlk) void floss_final(
    const float* __restrict__ partials, float* __restrict__ out) {
  float m = 0.f, r = 0.f, n = 0.f;
  for (int i = threadIdx.x; i < kNT; i += kBlk) {
    m += partials[i * 3 + 0];
    r += partials[i * 3 + 1];
    n += partials[i * 3 + 2];
  }
  __shared__ float sm[3][kBlk / 64];
  m = wave_reduce(m); r = wave_reduce(r); n = wave_reduce(n);
  const int lane = threadIdx.x & 63;
  const int w    = threadIdx.x >> 6;
  if (lane == 0) { sm[0][w] = m; sm[1][w] = r; sm[2][w] = n; }
  __syncthreads();
  if (threadIdx.x == 0) {
    float tm = 0.f, tr = 0.f, tn = 0.f;
#pragma unroll
    for (int j = 0; j < kBlk / 64; ++j) { tm += sm[0][j]; tr += sm[1][j]; tn += sm[2][j]; }
    out[0] = tm + 5.0f * tr / fmaxf(tn, 1.0f);
  }
}

}  // namespace

extern "C" void kernel_launch(void* const* d_in, const int* in_sizes, int n_in,
                              void* d_out, int out_size, void* d_ws, size_t ws_size,
                              hipStream_t stream) {
  const float* outs     = (const float*)d_in[0];
  const float* gres     = (const float*)d_in[1];
  const float* grids    = (const float*)d_in[2];
  const int*   nums_pos = (const int*)d_in[3];
  float* partials = (float*)d_ws;  // kNT * 3 floats = 33,792 B

  floss_fused<<<kNT, kBlk, 0, stream>>>(outs, gres, grids, nums_pos, partials);
  floss_final<<<1, kBlk, 0, stream>>>(partials, (float*)d_out);
}

// Round 3
// 67.063 us; speedup vs baseline: 2.9151x; 1.0562x over previous
//
#include <hip/hip_runtime.h>

namespace {

constexpr int   kC    = 80;
constexpr int   kD    = 8525;
constexpr int   kB    = 64;
constexpr float kEps  = 1e-6f;
constexpr int   kOC   = 85;                 // outs channels
constexpr int   kGC   = 88;                 // gres channels
constexpr int   kBlk  = 256;
constexpr int   kPB   = kD * kOC;           // 724625 floats of outs per batch
constexpr int   kSpb  = 32;                 // slices (blocks) per batch item
constexpr int   kRPS  = (kD + kSpb - 1) / kSpb;  // 267 rows per slice
constexpr int   kNT   = kB * kSpb;          // 2048 blocks total

__device__ __forceinline__ float wave_reduce(float v) {
#pragma unroll
  for (int o = 32; o > 0; o >>= 1) v += __shfl_down(v, o, 64);
  return v;
}

__device__ __forceinline__ float fast_rcp(float x) {
  return __builtin_amdgcn_rcpf(x);
}

// raw neg-loss term: p^2 * log(1-p+eps), p = sigmoid(x).  (negative value)
__device__ __forceinline__ float lneg_raw(float x) {
  const float t = __expf(-x);
  const float p = fast_rcp(1.0f + t);
  return p * p * __logf(1.0f - p + kEps);
}

__global__ __launch_bounds__(kBlk) void floss_fused(
    const float* __restrict__ outs, const float* __restrict__ gres,
    const float* __restrict__ grids, const int* __restrict__ nums_pos,
    float* __restrict__ partials) {
  const int bid = blockIdx.x;          // 0..2047
  const int tid = threadIdx.x;
  const int b   = bid >> 5;            // batch item
  const int sb  = bid & 31;            // slice within batch
  const int r0  = sb * kRPS;
  const int r1  = (r0 + kRPS < kD) ? r0 + kRPS : kD;
  const float scale = fast_rcp(64.0f * (float)nums_pos[b]);

  float pm = 0.f, pr = 0.f, pn = 0.f;

  // ---------------- phase A: branchless l_neg over ALL 85 channels --------
  {
    const int gA = b * kPB + r0 * kOC;
    const int gB = b * kPB + r1 * kOC;
    const int gv = (gA + 3) & ~3;                 // first float4-aligned idx
    const int nvec = (gB - gv) >> 2;
    const int gvend = gv + (nvec << 2);
    float a0 = 0.f, a1 = 0.f, a2 = 0.f, a3 = 0.f;
    if (tid < gv - gA)    a0 += lneg_raw(outs[gA + tid]);
    if (tid < gB - gvend) a1 += lneg_raw(outs[gvend + tid]);
#pragma unroll 2
    for (int v = tid; v < nvec; v += kBlk) {
      const float4 x = *(const float4*)(outs + gv + 4 * v);
      a0 += lneg_raw(x.x);
      a1 += lneg_raw(x.y);
      a2 += lneg_raw(x.z);
      a3 += lneg_raw(x.w);
    }
    pm += -0.75f * scale * ((a0 + a1) + (a2 + a3));
  }

  // ---------------- phase B: per-row terms (tail fix, conf, pos, GIoU) ----
  for (int r = r0 + tid; r < r1; r += kBlk) {
    const int row = b * kD + r;
    const float* orow = outs + (size_t)row * kOC;
    const float x80 = orow[80], x81 = orow[81], x82 = orow[82],
                x83 = orow[83], x84 = orow[84];
    // remove the 5 tail-channel contributions phase A wrongly added
    const float t5 = ((lneg_raw(x80) + lneg_raw(x81)) +
                      (lneg_raw(x82) + lneg_raw(x83))) + lneg_raw(x84);
    pm += 0.75f * scale * t5;

    const size_t gbase = (size_t)row * kGC;
    const float4 t0 = *(const float4*)(gres + gbase + 80);  // gc, l, t, r
    const float4 t1 = *(const float4*)(gres + gbase + 84);  // b, mpp, mpos, 0

    if (t1.y == 1.0f) {  // mask_pp -> conf BCE
      const float pc = fast_rcp(1.0f + __expf(-x80));
      pm += -5.0f * __logf(pc + kEps) * scale;
    }
    if (t1.z == 1.0f) {  // mask_pos
      pn += 1.0f;
      // locate one-hot label channel
      int lab = 0;
      const float4* gc = (const float4*)(gres + gbase);
#pragma unroll 5
      for (int j = 0; j < 20; ++j) {
        const float4 v = gc[j];
        if (v.x == 1.0f) lab = 4 * j;
        if (v.y == 1.0f) lab = 4 * j + 1;
        if (v.z == 1.0f) lab = 4 * j + 2;
        if (v.w == 1.0f) lab = 4 * j + 3;
      }
      // correction at label channel: + l_pos - l_neg
      const float x = orow[lab];
      const float t = __expf(-x);
      const float p = fast_rcp(1.0f + t);
      const float om = 1.0f - p;
      const float lp = -0.25f * om * om * __logf(p + kEps);
      const float ln = -0.75f * p * p * __logf(om + kEps);
      pm += (lp - ln) * scale;
      // GIoU regression (pred offsets are x81..x84)
      const float gx = grids[2 * r + 0];
      const float gy = grids[2 * r + 1];
      const float p0 = gx - x81, p1 = gy - x82;
      const float p2 = gx + x83, p3 = gy + x84;
      const float g0 = t0.y, g1 = t0.z, g2 = t0.w, g3 = t1.x;
      const float iw = fmaxf(fminf(p2, g2) - fmaxf(p0, g0), 0.f);
      const float ih = fmaxf(fminf(p3, g3) - fmaxf(p1, g1), 0.f);
      const float inter = iw * ih;
      const float ap = fmaxf(p2 - p0, 0.f) * fmaxf(p3 - p1, 0.f);
      const float ag = fmaxf(g2 - g0, 0.f) * fmaxf(g3 - g1, 0.f);
      const float un = ap + ag - inter;
      const float iou = inter * fast_rcp(un + kEps);
      const float ca = (fmaxf(p2, g2) - fminf(p0, g0)) *
                       (fmaxf(p3, g3) - fminf(p1, g1));
      const float giou = iou - (ca - un) * fast_rcp(ca + kEps);
      pr += (1.0f - giou) * t0.x;
    }
  }

  // ---------------- block reduction + partial write -----------------------
  __shared__ float sm[3][kBlk / 64];
  const float vm = wave_reduce(pm);
  const float vr = wave_reduce(pr);
  const float vn = wave_reduce(pn);
  const int lane = tid & 63;
  const int w    = tid >> 6;
  if (lane == 0) { sm[0][w] = vm; sm[1][w] = vr; sm[2][w] = vn; }
  __syncthreads();
  if (tid == 0) {
    float m = 0.f, r = 0.f, n = 0.f;
#pragma unroll
    for (int j = 0; j < kBlk / 64; ++j) { m += sm[0][j]; r += sm[1][j]; n += sm[2][j]; }
    partials[bid * 3 + 0] = m;
    partials[bid * 3 + 1] = r;
    partials[bid * 3 + 2] = n;
  }
}

__global__ __launch_bounds__(kBlk) void floss_final(
    const float* __restrict__ partials, float* __restrict__ out) {
  float m = 0.f, r = 0.f, n = 0.f;
  for (int i = threadIdx.x; i < kNT; i += kBlk) {
    m += partials[i * 3 + 0];
    r += partials[i * 3 + 1];
    n += partials[i * 3 + 2];
  }
  __shared__ float sm[3][kBlk / 64];
  m = wave_reduce(m); r = wave_reduce(r); n = wave_reduce(n);
  const int lane = threadIdx.x & 63;
  const int w    = threadIdx.x >> 6;
  if (lane == 0) { sm[0][w] = m; sm[1][w] = r; sm[2][w] = n; }
  __syncthreads();
  if (threadIdx.x == 0) {
    float tm = 0.f, tr = 0.f, tn = 0.f;
#pragma unroll
    for (int j = 0; j < kBlk / 64; ++j) { tm += sm[0][j]; tr += sm[1][j]; tn += sm[2][j]; }
    out[0] = tm + 5.0f * tr / fmaxf(tn, 1.0f);
  }
}

}  // namespace

extern "C" void kernel_launch(void* const* d_in, const int* in_sizes, int n_in,
                              void* d_out, int out_size, void* d_ws, size_t ws_size,
                              hipStream_t stream) {
  const float* outs     = (const float*)d_in[0];
  const float* gres     = (const float*)d_in[1];
  const float* grids    = (const float*)d_in[2];
  const int*   nums_pos = (const int*)d_in[3];
  float* partials = (float*)d_ws;  // kNT * 3 * 4 B = 24,576 B

  floss_fused<<<kNT, kBlk, 0, stream>>>(outs, gres, grids, nums_pos, partials);
  floss_final<<<1, kBlk, 0, stream>>>(partials, (float*)d_out);
}